// Round 18
// baseline (364.597 us; speedup 1.0000x reference)
//
#include <hip/hip_runtime.h>

typedef unsigned short u16;
typedef __bf16 bf16x8 __attribute__((ext_vector_type(8)));
typedef __bf16 bf16x4 __attribute__((ext_vector_type(4)));
typedef short s16x4 __attribute__((ext_vector_type(4)));
typedef float f32x4 __attribute__((ext_vector_type(4)));

union U4B8 { uint4 u; bf16x8 v; u16 s[8]; };
union U2S4 { uint2 u2; s16x4 s; bf16x4 h; };

__device__ __forceinline__ u16 f2b(float f) {
  union { float f; unsigned u; } x; x.f = f;
  unsigned u = x.u + 0x7fffu + ((x.u >> 16) & 1u);
  return (u16)(u >> 16);
}

// ---------------- fused prep: x fp32->bf16, W transposes ----------------
// blocks [0,8192): cvt x; [8192,8960): Wqkv transpose; [8960,9216): Wout.
__global__ __launch_bounds__(256) void prep(const float* __restrict__ x,
                                            const float* __restrict__ Wqkv,
                                            const float* __restrict__ Wout,
                                            u16* __restrict__ Xb,
                                            u16* __restrict__ WtQ,
                                            u16* __restrict__ WtO) {
  __shared__ u16 t[64 * 72];
  int bid = blockIdx.x;
  int tid = threadIdx.x;
  if (bid < 8192) {
    int i = bid * 256 + tid;
    float4 v = ((const float4*)x)[i];
    ushort4 h;
    h.x = f2b(v.x); h.y = f2b(v.y); h.z = f2b(v.z); h.w = f2b(v.w);
    ((ushort4*)Xb)[i] = h;
    return;
  }
  const float* in; u16* out; int N, bx, by;
  if (bid < 8960) {
    int tt = bid - 8192; bx = tt % 48; by = tt / 48; in = Wqkv; out = WtQ; N = 3072;
  } else {
    int tt = bid - 8960; bx = tt & 15; by = tt >> 4; in = Wout; out = WtO; N = 1024;
  }
  int k0 = by * 64, n0 = bx * 64;
#pragma unroll
  for (int p = 0; p < 4; ++p) {
    int idx = p * 256 + tid;
    int k = idx >> 4, ng = idx & 15;
    float4 v = *(const float4*)(in + (k0 + k) * N + n0 + ng * 4);
    t[(ng * 4 + 0) * 72 + k] = f2b(v.x);
    t[(ng * 4 + 1) * 72 + k] = f2b(v.y);
    t[(ng * 4 + 2) * 72 + k] = f2b(v.z);
    t[(ng * 4 + 3) * 72 + k] = f2b(v.w);
  }
  __syncthreads();
#pragma unroll
  for (int p = 0; p < 2; ++p) {
    int idx = p * 256 + tid;
    int n = idx >> 3, kg = (idx & 7) * 8;
    uint4 u = *(uint4*)(&t[n * 72 + kg]);
    *(uint4*)(out + (n0 + n) * 1024 + k0 + kg) = u;
  }
}

// ---------------- GEMM: C[M][N] = A[M][1024] @ Wt^T + bias ----------------
// 128x128 tile, BK=32, 4 waves. 3-buffer LDS rotation with counted
// s_waitcnt vmcnt(4) + ONE raw barrier per K-step (T4). r16 config (best).
// MODE 0: N=3072, out -> Q/K/V bf16 [64][2048][64], q scaled by 0.125*log2(e)
// MODE 1: N=1024, out -> fp32 d_out
template <int MODE>
__global__ __launch_bounds__(256) void gemm_bf16(const u16* __restrict__ A,
                                                 const u16* __restrict__ B,
                                                 const float* __restrict__ bias,
                                                 float* __restrict__ outf,
                                                 u16* __restrict__ Qo, u16* __restrict__ Ko,
                                                 u16* __restrict__ Vo) {
  __shared__ u16 a_lds[3 * 4096];
  __shared__ u16 b_lds[3 * 4096];
  int tid = threadIdx.x;
  int l = tid & 63, w = tid >> 6;
  int wr = (w >> 1) * 64, wc = (w & 1) * 64;
  int m0 = blockIdx.y * 128, n0 = blockIdx.x * 128;
  int r15 = l & 15;
  int ka = (l >> 4) * 8;
  int r0 = tid >> 2, kg0 = (tid & 3) * 8;
  f32x4 acc[4][4] = {};

#define STAGE_G(BUF, KT)                                                                     \
  {                                                                                          \
    int kk = (KT) * 32;                                                                      \
    __builtin_amdgcn_global_load_lds(                                                        \
        (const __attribute__((address_space(1))) void*)(A + (m0 + r0) * 1024 + kk + kg0),    \
        (__attribute__((address_space(3))) void*)(&a_lds[(BUF) * 4096 + tid * 8]), 16, 0, 0);\
    __builtin_amdgcn_global_load_lds(                                                        \
        (const __attribute__((address_space(1))) void*)(A + (m0 + 64 + r0) * 1024 + kk + kg0),\
        (__attribute__((address_space(3))) void*)(&a_lds[(BUF) * 4096 + 2048 + tid * 8]), 16, 0, 0);\
    __builtin_amdgcn_global_load_lds(                                                        \
        (const __attribute__((address_space(1))) void*)(B + (n0 + r0) * 1024 + kk + kg0),    \
        (__attribute__((address_space(3))) void*)(&b_lds[(BUF) * 4096 + tid * 8]), 16, 0, 0);\
    __builtin_amdgcn_global_load_lds(                                                        \
        (const __attribute__((address_space(1))) void*)(B + (n0 + 64 + r0) * 1024 + kk + kg0),\
        (__attribute__((address_space(3))) void*)(&b_lds[(BUF) * 4096 + 2048 + tid * 8]), 16, 0, 0);\
  }

  STAGE_G(0, 0);
  int cur = 0;
#pragma unroll 1
  for (int kt = 0; kt < 32; ++kt) {
    int nxt = (cur == 2) ? 0 : cur + 1;
    if (kt < 31) {
      STAGE_G(nxt, kt + 1);
      asm volatile("s_waitcnt vmcnt(4)" ::: "memory");
    } else {
      asm volatile("s_waitcnt vmcnt(0)" ::: "memory");
    }
    __builtin_amdgcn_s_barrier();
    __builtin_amdgcn_sched_barrier(0);
    int bo = cur * 4096;
    bf16x8 af[4], bf[4];
#pragma unroll
    for (int i = 0; i < 4; ++i) {
      U4B8 ua; ua.u = *(uint4*)(&a_lds[bo + (wr + i * 16 + r15) * 32 + ka]); af[i] = ua.v;
      U4B8 ub; ub.u = *(uint4*)(&b_lds[bo + (wc + i * 16 + r15) * 32 + ka]); bf[i] = ub.v;
    }
#pragma unroll
    for (int i = 0; i < 4; ++i)
#pragma unroll
      for (int j = 0; j < 4; ++j)
        acc[i][j] = __builtin_amdgcn_mfma_f32_16x16x32_bf16(af[i], bf[j], acc[i][j], 0, 0, 0);
    cur = nxt;
  }
#undef STAGE_G

  int rbase = (l >> 4) * 4;
#pragma unroll
  for (int i = 0; i < 4; ++i)
#pragma unroll
    for (int j = 0; j < 4; ++j) {
      int n = n0 + wc + j * 16 + r15;
      float bv = bias[n];
#pragma unroll
      for (int r = 0; r < 4; ++r) {
        int m = m0 + wr + i * 16 + rbase + r;
        float val = acc[i][j][r] + bv;
        if (MODE == 0) {
          int h = n / 192, rem = n % 192;
          int part = rem >> 6, d = rem & 63;
          int b = m >> 11, s = m & 2047;
          int off = (((b * 16 + h) * 2048) + s) * 64 + d;
          // q folded scale: 0.125 * log2(e) so attention can use exp2 directly
          u16 hv = f2b(part == 0 ? val * 0.180336880111f : val);
          if (part == 0) Qo[off] = hv;
          else if (part == 1) Ko[off] = hv;
          else Vo[off] = hv;
        } else {
          outf[m * 1024 + n] = val;
        }
      }
    }
}

// ---------------- flash attention ----------------
// 256 blocks x 1024 threads (16 waves, 512 q/block, 32 q/wave as 2 q-frags).
// 1 block/CU. NEW vs r16: KV tile = 128 rows (two 64-row subtiles/buffer) ->
// barriers 32->16, each __syncthreads vmcnt-drain amortized over 2x compute
// (r15's mechanism; r15 failed only on VGPR-cap spills at 140 regs — r16's
// role-split + ones-trick base sits at 64 regs, +~6 for the 2nd V reg fits
// the (1024,2)=128 cap). Staging ROLE-SPLIT: threads <512 stage K (2 gll),
// >=512 stage V (2 b128 loads + 16 scatter writes; same per-instruction
// 64-lane patterns as r10/r16, 0 conflicts measured). lsum via MFMA
// ones-trick. XCD remap: xcd=bid&7, bh=xcd*8+(bid>>5), qb=(bid>>3)&3.
// Swapped QK^T (16x16x32); PV via mfma_f32_16x16x16bf16_1k, reg-resident P.
// exp2 via __builtin_amdgcn_exp2f. V^T [d][kv] swz4(d)=((d>>3)^d)&15;
// K [kv][64] row&7-swizzle via pre-swizzled gll source.
// LDS 64KB: K dbuf [0,16384) u16 (buf b at b*8192, sub s at +s*4096),
// V^T dbuf [16384,32768); epilogue staging reuses all after final sync.
__global__ __launch_bounds__(1024, 2) void attn_fwd(const u16* __restrict__ Q,
                                                    const u16* __restrict__ K,
                                                    const u16* __restrict__ V,
                                                    u16* __restrict__ O) {
  __shared__ u16 lds[32768];
  int tid = threadIdx.x;
  int l = tid & 63, w = tid >> 6;
  int g = l >> 4, r15 = l & 15, r7 = r15 & 7;
  int bid = blockIdx.x;
  int qb = (bid >> 3) & 3;
  int bh = (bid & 7) * 8 + (bid >> 5);
  const u16* Kb = K + bh * 131072;
  const u16* Vb = V + bh * 131072;
  int ka = g * 8;
  int qbase = qb * 512 + w * 32;
  U4B8 t0, t1, t2, t3;
  t0.u = *(const uint4*)(Q + bh * 131072 + (qbase + r15) * 64 + ka);
  t1.u = *(const uint4*)(Q + bh * 131072 + (qbase + r15) * 64 + 32 + ka);
  t2.u = *(const uint4*)(Q + bh * 131072 + (qbase + 16 + r15) * 64 + ka);
  t3.u = *(const uint4*)(Q + bh * 131072 + (qbase + 16 + r15) * 64 + 32 + ka);
  bf16x8 qf00 = t0.v, qf01 = t1.v, qf10 = t2.v, qf11 = t3.v;

  // K b128 read addrs within 64-row subtile: row=c*16+r15, chunk (g)^(row&7)
  int kaddr[4];
#pragma unroll
  for (int c = 0; c < 4; ++c) kaddr[c] = (c * 16 + r15) * 64 + ((g ^ r7) << 3);
  // V^T b64 read base within subtile: d=16dq+r15; addr(c) = vaddr0 ^ (16c)
  int vaddr0[4];
#pragma unroll
  for (int dq = 0; dq < 4; ++dq) {
    int d = r15 + 16 * dq;
    int vsw = ((d >> 3) ^ d) & 15;
    vaddr0[dq] = d * 64 + ((g ^ vsw) << 2);
  }

  // staging role split
  int st = tid & 511;
  bool kRole = tid < 512;
  // K role: source chunk pre-swizzled (m173): row=st>>3, chunk=(st&7)^(row&7).
  int krow0 = st >> 3;
  int kcg = (((st & 7) ^ (krow0 & 7)) << 3);
  // V role: loads V rows sr0 / sr0+64, scatters transposed+swizzled.
  int sr0 = st >> 3, sdg = (st & 7) * 8;
  int vwa[8];
#pragma unroll
  for (int i = 0; i < 8; ++i) {
    int d = sdg + i;
    int sw = ((d >> 3) ^ d) & 15;
    vwa[i] = d * 64 + ((((sr0 >> 2)) ^ sw) << 2) + (sr0 & 3);
  }
  U4B8 vreg0, vreg1;

  // TN = 128-row tile index (0..15); BUF in {0,1}
#define STAGE(BUF, TN)                                                                     \
  {                                                                                        \
    int kv0 = (TN) * 128;                                                                  \
    if (kRole) {                                                                           \
      __builtin_amdgcn_global_load_lds(                                                    \
          (const __attribute__((address_space(1))) void*)(Kb + (kv0 + krow0) * 64 + kcg),  \
          (__attribute__((address_space(3))) void*)(&lds[(BUF) * 8192 + st * 8]), 16, 0, 0);\
      __builtin_amdgcn_global_load_lds(                                                    \
          (const __attribute__((address_space(1))) void*)(Kb + (kv0 + 64 + krow0) * 64 + kcg),\
          (__attribute__((address_space(3))) void*)(&lds[(BUF) * 8192 + 4096 + st * 8]), 16, 0, 0);\
    } else {                                                                               \
      vreg0.u = *(const uint4*)(Vb + (kv0 + sr0) * 64 + sdg);                              \
      vreg1.u = *(const uint4*)(Vb + (kv0 + 64 + sr0) * 64 + sdg);                         \
    }                                                                                      \
  }

#define WRITEV(BUF)                                                                        \
  {                                                                                        \
    if (!kRole) {                                                                          \
      _Pragma("unroll") for (int i = 0; i < 8; ++i) {                                      \
        lds[16384 + (BUF) * 8192 + vwa[i]] = vreg0.s[i];                                   \
        lds[16384 + (BUF) * 8192 + 4096 + vwa[i]] = vreg1.s[i];                            \
      }                                                                                    \
    }                                                                                      \
  }

  s16x4 vone;
  vone[0] = (short)0x3F80; vone[1] = (short)0x3F80;
  vone[2] = (short)0x3F80; vone[3] = (short)0x3F80;
  f32x4 lacc0 = {}, lacc1 = {};
  f32x4 o0[4] = {}, o1[4] = {};

#define COMPUTE(KOFF, VOFF)                                                                \
  {                                                                                        \
    _Pragma("unroll") for (int c = 0; c < 4; ++c) {                                        \
      U4B8 k0, k1;                                                                         \
      k0.u = *(const uint4*)(&lds[(KOFF) + kaddr[c]]);                                     \
      k1.u = *(const uint4*)(&lds[(KOFF) + (kaddr[c] ^ 32)]);                              \
      f32x4 z0 = {}, z1 = {};                                                              \
      z0 = __builtin_amdgcn_mfma_f32_16x16x32_bf16(k0.v, qf00, z0, 0, 0, 0);               \
      z0 = __builtin_amdgcn_mfma_f32_16x16x32_bf16(k1.v, qf01, z0, 0, 0, 0);               \
      z1 = __builtin_amdgcn_mfma_f32_16x16x32_bf16(k0.v, qf10, z1, 0, 0, 0);               \
      z1 = __builtin_amdgcn_mfma_f32_16x16x32_bf16(k1.v, qf11, z1, 0, 0, 0);               \
      float a0 = __builtin_amdgcn_exp2f(z0[0]), a1 = __builtin_amdgcn_exp2f(z0[1]);        \
      float a2 = __builtin_amdgcn_exp2f(z0[2]), a3 = __builtin_amdgcn_exp2f(z0[3]);        \
      U2S4 pa0;                                                                            \
      pa0.h[0] = (__bf16)a0; pa0.h[1] = (__bf16)a1;                                        \
      pa0.h[2] = (__bf16)a2; pa0.h[3] = (__bf16)a3;                                        \
      float b0 = __builtin_amdgcn_exp2f(z1[0]), b1 = __builtin_amdgcn_exp2f(z1[1]);        \
      float b2 = __builtin_amdgcn_exp2f(z1[2]), b3 = __builtin_amdgcn_exp2f(z1[3]);        \
      U2S4 pa1;                                                                            \
      pa1.h[0] = (__bf16)b0; pa1.h[1] = (__bf16)b1;                                        \
      pa1.h[2] = (__bf16)b2; pa1.h[3] = (__bf16)b3;                                        \
      lacc0 = __builtin_amdgcn_mfma_f32_16x16x16bf16_1k(pa0.s, vone, lacc0, 0, 0, 0);      \
      lacc1 = __builtin_amdgcn_mfma_f32_16x16x16bf16_1k(pa1.s, vone, lacc1, 0, 0, 0);      \
      _Pragma("unroll") for (int dq = 0; dq < 4; ++dq) {                                   \
        U2S4 vb;                                                                           \
        vb.u2 = *(const uint2*)(&lds[(VOFF) + (vaddr0[dq] ^ (16 * c))]);                   \
        o0[dq] = __builtin_amdgcn_mfma_f32_16x16x16bf16_1k(pa0.s, vb.s, o0[dq], 0, 0, 0);  \
        o1[dq] = __builtin_amdgcn_mfma_f32_16x16x16bf16_1k(pa1.s, vb.s, o1[dq], 0, 0, 0);  \
      }                                                                                    \
    }                                                                                      \
  }

  STAGE(0, 0);
  WRITEV(0);
#pragma unroll 1
  for (int tt = 0; tt < 8; ++tt) {
    __syncthreads();
    STAGE(1, 2 * tt + 1);
    COMPUTE(0, 16384);          // buf0 sub0
    COMPUTE(4096, 20480);       // buf0 sub1
    WRITEV(1);
    __syncthreads();
    if (tt < 7) STAGE(0, 2 * tt + 2);
    COMPUTE(8192, 24576);       // buf1 sub0
    COMPUTE(12288, 28672);      // buf1 sub1
    if (tt < 7) WRITEV(0);
  }
#undef STAGE
#undef WRITEV
#undef COMPUTE

  // per-lane inverse sums: lacc[j] holds l of q-row 4g+j (C/D row = 4g+reg)
  float c0[4], c1[4];
#pragma unroll
  for (int j = 0; j < 4; ++j) {
    c0[j] = 1.f / lacc0[j];
    c1[j] = 1.f / lacc1[j];
  }
  // ---- staged O epilogue: per-wave 32x64 bf16 tile in reused LDS -> full-line stores ----
  __syncthreads();   // all waves done reading K/V buffers before reuse
  u16* stg = lds + w * 2048;   // 16 waves x 2048 u16 = 32768 (whole lds)
#pragma unroll
  for (int j = 0; j < 4; ++j) {
    int rr0 = 4 * g + j;        // (rr0>>2)&3 == g
    int rr1 = 16 + 4 * g + j;   // (rr1>>2)&3 == g
#pragma unroll
    for (int dq = 0; dq < 4; ++dq) {
      int pc = ((dq ^ g) << 4) + r15;
      stg[rr0 * 64 + pc] = f2b(o0[dq][j] * c0[j]);
      stg[rr1 * 64 + pc] = f2b(o1[dq][j] * c1[j]);
    }
  }
  int b = bh >> 4, h = bh & 15;
  int colpair = (l & 31) * 2;
  int rowsel = l >> 5;
#pragma unroll
  for (int it = 0; it < 16; ++it) {
    int rr = 2 * it + rowsel;
    int phys = rr * 64 + (((colpair >> 4) ^ ((rr >> 2) & 3)) << 4) + (colpair & 15);
    unsigned pv = *(const unsigned*)(&stg[phys]);
    int row = qbase + rr;
    *(unsigned*)(&O[(b * 2048 + row) * 1024 + h * 64 + colpair]) = pv;
  }
}

extern "C" void kernel_launch(void* const* d_in, const int* in_sizes, int n_in,
                              void* d_out, int out_size, void* d_ws, size_t ws_size,
                              hipStream_t stream) {
  const float* x = (const float*)d_in[0];
  const float* Wqkv = (const float*)d_in[1];
  const float* bqkv = (const float*)d_in[2];
  const float* Wout = (const float*)d_in[3];
  const float* bout = (const float*)d_in[4];
  float* out = (float*)d_out;

  u16* ws = (u16*)d_ws;
  u16* WtQ = ws;                    // 3072*1024
  u16* WtO = WtQ + 3072 * 1024;     // 1024*1024
  u16* Xb  = WtO + 1024 * 1024;     // 8192*1024
  u16* Qw  = Xb + 8192 * 1024;      // 64*2048*64
  u16* Kw  = Qw + 64 * 2048 * 64;
  u16* Vw  = Kw + 64 * 2048 * 64;
  u16* Aw  = Vw + 64 * 2048 * 64;   // 8192*1024

  prep<<<9216, 256, 0, stream>>>(x, Wqkv, Wout, Xb, WtQ, WtO);
  gemm_bf16<0><<<dim3(24, 64), 256, 0, stream>>>(Xb, WtQ, bqkv, nullptr, Qw, Kw, Vw);
  attn_fwd<<<256, 1024, 0, stream>>>(Qw, Kw, Vw, Aw);
  gemm_bf16<1><<<dim3(8, 64), 256, 0, stream>>>(Aw, WtO, bout, out, nullptr, nullptr, nullptr);
}

// Round 19
// 362.078 us; speedup vs baseline: 1.0070x; 1.0070x over previous
//
#include <hip/hip_runtime.h>

typedef unsigned short u16;
typedef __bf16 bf16x8 __attribute__((ext_vector_type(8)));
typedef __bf16 bf16x4 __attribute__((ext_vector_type(4)));
typedef short s16x4 __attribute__((ext_vector_type(4)));
typedef float f32x4 __attribute__((ext_vector_type(4)));

union U4B8 { uint4 u; bf16x8 v; u16 s[8]; };
union U2S4 { uint2 u2; s16x4 s; bf16x4 h; };

__device__ __forceinline__ u16 f2b(float f) {
  union { float f; unsigned u; } x; x.f = f;
  unsigned u = x.u + 0x7fffu + ((x.u >> 16) & 1u);
  return (u16)(u >> 16);
}

// ---------------- fused prep: x fp32->bf16, W transposes ----------------
// blocks [0,8192): cvt x; [8192,8960): Wqkv transpose; [8960,9216): Wout.
__global__ __launch_bounds__(256) void prep(const float* __restrict__ x,
                                            const float* __restrict__ Wqkv,
                                            const float* __restrict__ Wout,
                                            u16* __restrict__ Xb,
                                            u16* __restrict__ WtQ,
                                            u16* __restrict__ WtO) {
  __shared__ u16 t[64 * 72];
  int bid = blockIdx.x;
  int tid = threadIdx.x;
  if (bid < 8192) {
    int i = bid * 256 + tid;
    float4 v = ((const float4*)x)[i];
    ushort4 h;
    h.x = f2b(v.x); h.y = f2b(v.y); h.z = f2b(v.z); h.w = f2b(v.w);
    ((ushort4*)Xb)[i] = h;
    return;
  }
  const float* in; u16* out; int N, bx, by;
  if (bid < 8960) {
    int tt = bid - 8192; bx = tt % 48; by = tt / 48; in = Wqkv; out = WtQ; N = 3072;
  } else {
    int tt = bid - 8960; bx = tt & 15; by = tt >> 4; in = Wout; out = WtO; N = 1024;
  }
  int k0 = by * 64, n0 = bx * 64;
#pragma unroll
  for (int p = 0; p < 4; ++p) {
    int idx = p * 256 + tid;
    int k = idx >> 4, ng = idx & 15;
    float4 v = *(const float4*)(in + (k0 + k) * N + n0 + ng * 4);
    t[(ng * 4 + 0) * 72 + k] = f2b(v.x);
    t[(ng * 4 + 1) * 72 + k] = f2b(v.y);
    t[(ng * 4 + 2) * 72 + k] = f2b(v.z);
    t[(ng * 4 + 3) * 72 + k] = f2b(v.w);
  }
  __syncthreads();
#pragma unroll
  for (int p = 0; p < 2; ++p) {
    int idx = p * 256 + tid;
    int n = idx >> 3, kg = (idx & 7) * 8;
    uint4 u = *(uint4*)(&t[n * 72 + kg]);
    *(uint4*)(out + (n0 + n) * 1024 + k0 + kg) = u;
  }
}

// ---------------- GEMM: C[M][N] = A[M][1024] @ Wt^T + bias ----------------
// 128x128 tile, BK=32, 4 waves. 3-buffer LDS rotation with counted
// s_waitcnt vmcnt(4) + ONE raw barrier per K-step (T4). r16 config (best).
// MODE 0: N=3072, out -> Q/K/V bf16 [64][2048][64], q scaled by 0.125*log2(e)
// MODE 1: N=1024, out -> fp32 d_out
template <int MODE>
__global__ __launch_bounds__(256) void gemm_bf16(const u16* __restrict__ A,
                                                 const u16* __restrict__ B,
                                                 const float* __restrict__ bias,
                                                 float* __restrict__ outf,
                                                 u16* __restrict__ Qo, u16* __restrict__ Ko,
                                                 u16* __restrict__ Vo) {
  __shared__ u16 a_lds[3 * 4096];
  __shared__ u16 b_lds[3 * 4096];
  int tid = threadIdx.x;
  int l = tid & 63, w = tid >> 6;
  int wr = (w >> 1) * 64, wc = (w & 1) * 64;
  int m0 = blockIdx.y * 128, n0 = blockIdx.x * 128;
  int r15 = l & 15;
  int ka = (l >> 4) * 8;
  int r0 = tid >> 2, kg0 = (tid & 3) * 8;
  f32x4 acc[4][4] = {};

#define STAGE_G(BUF, KT)                                                                     \
  {                                                                                          \
    int kk = (KT) * 32;                                                                      \
    __builtin_amdgcn_global_load_lds(                                                        \
        (const __attribute__((address_space(1))) void*)(A + (m0 + r0) * 1024 + kk + kg0),    \
        (__attribute__((address_space(3))) void*)(&a_lds[(BUF) * 4096 + tid * 8]), 16, 0, 0);\
    __builtin_amdgcn_global_load_lds(                                                        \
        (const __attribute__((address_space(1))) void*)(A + (m0 + 64 + r0) * 1024 + kk + kg0),\
        (__attribute__((address_space(3))) void*)(&a_lds[(BUF) * 4096 + 2048 + tid * 8]), 16, 0, 0);\
    __builtin_amdgcn_global_load_lds(                                                        \
        (const __attribute__((address_space(1))) void*)(B + (n0 + r0) * 1024 + kk + kg0),    \
        (__attribute__((address_space(3))) void*)(&b_lds[(BUF) * 4096 + tid * 8]), 16, 0, 0);\
    __builtin_amdgcn_global_load_lds(                                                        \
        (const __attribute__((address_space(1))) void*)(B + (n0 + 64 + r0) * 1024 + kk + kg0),\
        (__attribute__((address_space(3))) void*)(&b_lds[(BUF) * 4096 + 2048 + tid * 8]), 16, 0, 0);\
  }

  STAGE_G(0, 0);
  int cur = 0;
#pragma unroll 1
  for (int kt = 0; kt < 32; ++kt) {
    int nxt = (cur == 2) ? 0 : cur + 1;
    if (kt < 31) {
      STAGE_G(nxt, kt + 1);
      asm volatile("s_waitcnt vmcnt(4)" ::: "memory");
    } else {
      asm volatile("s_waitcnt vmcnt(0)" ::: "memory");
    }
    __builtin_amdgcn_s_barrier();
    __builtin_amdgcn_sched_barrier(0);
    int bo = cur * 4096;
    bf16x8 af[4], bf[4];
#pragma unroll
    for (int i = 0; i < 4; ++i) {
      U4B8 ua; ua.u = *(uint4*)(&a_lds[bo + (wr + i * 16 + r15) * 32 + ka]); af[i] = ua.v;
      U4B8 ub; ub.u = *(uint4*)(&b_lds[bo + (wc + i * 16 + r15) * 32 + ka]); bf[i] = ub.v;
    }
#pragma unroll
    for (int i = 0; i < 4; ++i)
#pragma unroll
      for (int j = 0; j < 4; ++j)
        acc[i][j] = __builtin_amdgcn_mfma_f32_16x16x32_bf16(af[i], bf[j], acc[i][j], 0, 0, 0);
    cur = nxt;
  }
#undef STAGE_G

  int rbase = (l >> 4) * 4;
#pragma unroll
  for (int i = 0; i < 4; ++i)
#pragma unroll
    for (int j = 0; j < 4; ++j) {
      int n = n0 + wc + j * 16 + r15;
      float bv = bias[n];
#pragma unroll
      for (int r = 0; r < 4; ++r) {
        int m = m0 + wr + i * 16 + rbase + r;
        float val = acc[i][j][r] + bv;
        if (MODE == 0) {
          int h = n / 192, rem = n % 192;
          int part = rem >> 6, d = rem & 63;
          int b = m >> 11, s = m & 2047;
          int off = (((b * 16 + h) * 2048) + s) * 64 + d;
          // q folded scale: 0.125 * log2(e) so attention can use exp2 directly
          u16 hv = f2b(part == 0 ? val * 0.180336880111f : val);
          if (part == 0) Qo[off] = hv;
          else if (part == 1) Ko[off] = hv;
          else Vo[off] = hv;
        } else {
          outf[m * 1024 + n] = val;
        }
      }
    }
}

// ---------------- flash attention ----------------
// 256 blocks x 1024 threads (16 waves, 512 q/block, 32 q/wave as 2 q-frags).
// 1 block/CU. KV tile = 128 rows (two 64-row subtiles/buffer) -> barriers
// 32->16, each __syncthreads vmcnt-drain amortized over 2x compute.
// launch_bounds(1024,1): empirical VGPR-cap law cap=512/(waves/SIMD implied);
// (1024,2) implied 8 waves/SIMD -> 64-reg cap -> r18 spilled (FETCH 464MB).
// A 1024-thread block is HW-capped at 128 VGPR anyway (16 waves must
// co-reside = 4/SIMD), and grid 256 = 1 block/CU, so (1024,1) loses nothing.
// Staging ROLE-SPLIT: threads <512 stage K (2 gll), >=512 stage V (2 b128
// loads + 16 scatter writes; per-instruction 64-lane patterns identical to
// r10/r16, 0 conflicts measured). lsum via MFMA ones-trick. XCD remap:
// xcd=bid&7, bh=xcd*8+(bid>>5), qb=(bid>>3)&3. Swapped QK^T (16x16x32);
// PV via mfma_f32_16x16x16bf16_1k, reg-resident P. exp2 via
// __builtin_amdgcn_exp2f. V^T [d][kv] swz4(d)=((d>>3)^d)&15; K [kv][64]
// row&7-swizzle via pre-swizzled gll source.
// LDS 64KB: K dbuf [0,16384) u16 (buf b at b*8192, sub s at +s*4096),
// V^T dbuf [16384,32768); epilogue staging reuses all after final sync.
__global__ __launch_bounds__(1024, 1) void attn_fwd(const u16* __restrict__ Q,
                                                    const u16* __restrict__ K,
                                                    const u16* __restrict__ V,
                                                    u16* __restrict__ O) {
  __shared__ u16 lds[32768];
  int tid = threadIdx.x;
  int l = tid & 63, w = tid >> 6;
  int g = l >> 4, r15 = l & 15, r7 = r15 & 7;
  int bid = blockIdx.x;
  int qb = (bid >> 3) & 3;
  int bh = (bid & 7) * 8 + (bid >> 5);
  const u16* Kb = K + bh * 131072;
  const u16* Vb = V + bh * 131072;
  int ka = g * 8;
  int qbase = qb * 512 + w * 32;
  U4B8 t0, t1, t2, t3;
  t0.u = *(const uint4*)(Q + bh * 131072 + (qbase + r15) * 64 + ka);
  t1.u = *(const uint4*)(Q + bh * 131072 + (qbase + r15) * 64 + 32 + ka);
  t2.u = *(const uint4*)(Q + bh * 131072 + (qbase + 16 + r15) * 64 + ka);
  t3.u = *(const uint4*)(Q + bh * 131072 + (qbase + 16 + r15) * 64 + 32 + ka);
  bf16x8 qf00 = t0.v, qf01 = t1.v, qf10 = t2.v, qf11 = t3.v;

  // K b128 read addrs within 64-row subtile: row=c*16+r15, chunk (g)^(row&7)
  int kaddr[4];
#pragma unroll
  for (int c = 0; c < 4; ++c) kaddr[c] = (c * 16 + r15) * 64 + ((g ^ r7) << 3);
  // V^T b64 read base within subtile: d=16dq+r15; addr(c) = vaddr0 ^ (16c)
  int vaddr0[4];
#pragma unroll
  for (int dq = 0; dq < 4; ++dq) {
    int d = r15 + 16 * dq;
    int vsw = ((d >> 3) ^ d) & 15;
    vaddr0[dq] = d * 64 + ((g ^ vsw) << 2);
  }

  // staging role split
  int st = tid & 511;
  bool kRole = tid < 512;
  // K role: source chunk pre-swizzled (m173): row=st>>3, chunk=(st&7)^(row&7).
  int krow0 = st >> 3;
  int kcg = (((st & 7) ^ (krow0 & 7)) << 3);
  // V role: loads V rows sr0 / sr0+64, scatters transposed+swizzled.
  int sr0 = st >> 3, sdg = (st & 7) * 8;
  int vwa[8];
#pragma unroll
  for (int i = 0; i < 8; ++i) {
    int d = sdg + i;
    int sw = ((d >> 3) ^ d) & 15;
    vwa[i] = d * 64 + ((((sr0 >> 2)) ^ sw) << 2) + (sr0 & 3);
  }
  U4B8 vreg0, vreg1;

  // TN = 128-row tile index (0..15); BUF in {0,1}
#define STAGE(BUF, TN)                                                                     \
  {                                                                                        \
    int kv0 = (TN) * 128;                                                                  \
    if (kRole) {                                                                           \
      __builtin_amdgcn_global_load_lds(                                                    \
          (const __attribute__((address_space(1))) void*)(Kb + (kv0 + krow0) * 64 + kcg),  \
          (__attribute__((address_space(3))) void*)(&lds[(BUF) * 8192 + st * 8]), 16, 0, 0);\
      __builtin_amdgcn_global_load_lds(                                                    \
          (const __attribute__((address_space(1))) void*)(Kb + (kv0 + 64 + krow0) * 64 + kcg),\
          (__attribute__((address_space(3))) void*)(&lds[(BUF) * 8192 + 4096 + st * 8]), 16, 0, 0);\
    } else {                                                                               \
      vreg0.u = *(const uint4*)(Vb + (kv0 + sr0) * 64 + sdg);                              \
      vreg1.u = *(const uint4*)(Vb + (kv0 + 64 + sr0) * 64 + sdg);                         \
    }                                                                                      \
  }

#define WRITEV(BUF)                                                                        \
  {                                                                                        \
    if (!kRole) {                                                                          \
      _Pragma("unroll") for (int i = 0; i < 8; ++i) {                                      \
        lds[16384 + (BUF) * 8192 + vwa[i]] = vreg0.s[i];                                   \
        lds[16384 + (BUF) * 8192 + 4096 + vwa[i]] = vreg1.s[i];                            \
      }                                                                                    \
    }                                                                                      \
  }

  s16x4 vone;
  vone[0] = (short)0x3F80; vone[1] = (short)0x3F80;
  vone[2] = (short)0x3F80; vone[3] = (short)0x3F80;
  f32x4 lacc0 = {}, lacc1 = {};
  f32x4 o0[4] = {}, o1[4] = {};

#define COMPUTE(KOFF, VOFF)                                                                \
  {                                                                                        \
    _Pragma("unroll") for (int c = 0; c < 4; ++c) {                                        \
      U4B8 k0, k1;                                                                         \
      k0.u = *(const uint4*)(&lds[(KOFF) + kaddr[c]]);                                     \
      k1.u = *(const uint4*)(&lds[(KOFF) + (kaddr[c] ^ 32)]);                              \
      f32x4 z0 = {}, z1 = {};                                                              \
      z0 = __builtin_amdgcn_mfma_f32_16x16x32_bf16(k0.v, qf00, z0, 0, 0, 0);               \
      z0 = __builtin_amdgcn_mfma_f32_16x16x32_bf16(k1.v, qf01, z0, 0, 0, 0);               \
      z1 = __builtin_amdgcn_mfma_f32_16x16x32_bf16(k0.v, qf10, z1, 0, 0, 0);               \
      z1 = __builtin_amdgcn_mfma_f32_16x16x32_bf16(k1.v, qf11, z1, 0, 0, 0);               \
      float a0 = __builtin_amdgcn_exp2f(z0[0]), a1 = __builtin_amdgcn_exp2f(z0[1]);        \
      float a2 = __builtin_amdgcn_exp2f(z0[2]), a3 = __builtin_amdgcn_exp2f(z0[3]);        \
      U2S4 pa0;                                                                            \
      pa0.h[0] = (__bf16)a0; pa0.h[1] = (__bf16)a1;                                        \
      pa0.h[2] = (__bf16)a2; pa0.h[3] = (__bf16)a3;                                        \
      float b0 = __builtin_amdgcn_exp2f(z1[0]), b1 = __builtin_amdgcn_exp2f(z1[1]);        \
      float b2 = __builtin_amdgcn_exp2f(z1[2]), b3 = __builtin_amdgcn_exp2f(z1[3]);        \
      U2S4 pa1;                                                                            \
      pa1.h[0] = (__bf16)b0; pa1.h[1] = (__bf16)b1;                                        \
      pa1.h[2] = (__bf16)b2; pa1.h[3] = (__bf16)b3;                                        \
      lacc0 = __builtin_amdgcn_mfma_f32_16x16x16bf16_1k(pa0.s, vone, lacc0, 0, 0, 0);      \
      lacc1 = __builtin_amdgcn_mfma_f32_16x16x16bf16_1k(pa1.s, vone, lacc1, 0, 0, 0);      \
      _Pragma("unroll") for (int dq = 0; dq < 4; ++dq) {                                   \
        U2S4 vb;                                                                           \
        vb.u2 = *(const uint2*)(&lds[(VOFF) + (vaddr0[dq] ^ (16 * c))]);                   \
        o0[dq] = __builtin_amdgcn_mfma_f32_16x16x16bf16_1k(pa0.s, vb.s, o0[dq], 0, 0, 0);  \
        o1[dq] = __builtin_amdgcn_mfma_f32_16x16x16bf16_1k(pa1.s, vb.s, o1[dq], 0, 0, 0);  \
      }                                                                                    \
    }                                                                                      \
  }

  STAGE(0, 0);
  WRITEV(0);
#pragma unroll 1
  for (int tt = 0; tt < 8; ++tt) {
    __syncthreads();
    STAGE(1, 2 * tt + 1);
    COMPUTE(0, 16384);          // buf0 sub0
    COMPUTE(4096, 20480);       // buf0 sub1
    WRITEV(1);
    __syncthreads();
    if (tt < 7) STAGE(0, 2 * tt + 2);
    COMPUTE(8192, 24576);       // buf1 sub0
    COMPUTE(12288, 28672);      // buf1 sub1
    if (tt < 7) WRITEV(0);
  }
#undef STAGE
#undef WRITEV
#undef COMPUTE

  // per-lane inverse sums: lacc[j] holds l of q-row 4g+j (C/D row = 4g+reg)
  float c0[4], c1[4];
#pragma unroll
  for (int j = 0; j < 4; ++j) {
    c0[j] = 1.f / lacc0[j];
    c1[j] = 1.f / lacc1[j];
  }
  // ---- staged O epilogue: per-wave 32x64 bf16 tile in reused LDS -> full-line stores ----
  __syncthreads();   // all waves done reading K/V buffers before reuse
  u16* stg = lds + w * 2048;   // 16 waves x 2048 u16 = 32768 (whole lds)
#pragma unroll
  for (int j = 0; j < 4; ++j) {
    int rr0 = 4 * g + j;        // (rr0>>2)&3 == g
    int rr1 = 16 + 4 * g + j;   // (rr1>>2)&3 == g
#pragma unroll
    for (int dq = 0; dq < 4; ++dq) {
      int pc = ((dq ^ g) << 4) + r15;
      stg[rr0 * 64 + pc] = f2b(o0[dq][j] * c0[j]);
      stg[rr1 * 64 + pc] = f2b(o1[dq][j] * c1[j]);
    }
  }
  int b = bh >> 4, h = bh & 15;
  int colpair = (l & 31) * 2;
  int rowsel = l >> 5;
#pragma unroll
  for (int it = 0; it < 16; ++it) {
    int rr = 2 * it + rowsel;
    int phys = rr * 64 + (((colpair >> 4) ^ ((rr >> 2) & 3)) << 4) + (colpair & 15);
    unsigned pv = *(const unsigned*)(&stg[phys]);
    int row = qbase + rr;
    *(unsigned*)(&O[(b * 2048 + row) * 1024 + h * 64 + colpair]) = pv;
  }
}

extern "C" void kernel_launch(void* const* d_in, const int* in_sizes, int n_in,
                              void* d_out, int out_size, void* d_ws, size_t ws_size,
                              hipStream_t stream) {
  const float* x = (const float*)d_in[0];
  const float* Wqkv = (const float*)d_in[1];
  const float* bqkv = (const float*)d_in[2];
  const float* Wout = (const float*)d_in[3];
  const float* bout = (const float*)d_in[4];
  float* out = (float*)d_out;

  u16* ws = (u16*)d_ws;
  u16* WtQ = ws;                    // 3072*1024
  u16* WtO = WtQ + 3072 * 1024;     // 1024*1024
  u16* Xb  = WtO + 1024 * 1024;     // 8192*1024
  u16* Qw  = Xb + 8192 * 1024;      // 64*2048*64
  u16* Kw  = Qw + 64 * 2048 * 64;
  u16* Vw  = Kw + 64 * 2048 * 64;
  u16* Aw  = Vw + 64 * 2048 * 64;   // 8192*1024

  prep<<<9216, 256, 0, stream>>>(x, Wqkv, Wout, Xb, WtQ, WtO);
  gemm_bf16<0><<<dim3(24, 64), 256, 0, stream>>>(Xb, WtQ, bqkv, nullptr, Qw, Kw, Vw);
  attn_fwd<<<256, 1024, 0, stream>>>(Qw, Kw, Vw, Aw);
  gemm_bf16<1><<<dim3(8, 64), 256, 0, stream>>>(Aw, WtO, bout, out, nullptr, nullptr, nullptr);
}

// Round 20
// 198.682 us; speedup vs baseline: 1.8351x; 1.8224x over previous
//
#include <hip/hip_runtime.h>

typedef unsigned short u16;
typedef __bf16 bf16x8 __attribute__((ext_vector_type(8)));
typedef __bf16 bf16x4 __attribute__((ext_vector_type(4)));
typedef short s16x4 __attribute__((ext_vector_type(4)));
typedef float f32x4 __attribute__((ext_vector_type(4)));

union U4B8 { uint4 u; bf16x8 v; u16 s[8]; };
union U2S4 { uint2 u2; s16x4 s; bf16x4 h; };

__device__ __forceinline__ u16 f2b(float f) {
  union { float f; unsigned u; } x; x.f = f;
  unsigned u = x.u + 0x7fffu + ((x.u >> 16) & 1u);
  return (u16)(u >> 16);
}

// ---------------- fused prep: x fp32->bf16, W transposes ----------------
// blocks [0,8192): cvt x; [8192,8960): Wqkv transpose; [8960,9216): Wout.
__global__ __launch_bounds__(256) void prep(const float* __restrict__ x,
                                            const float* __restrict__ Wqkv,
                                            const float* __restrict__ Wout,
                                            u16* __restrict__ Xb,
                                            u16* __restrict__ WtQ,
                                            u16* __restrict__ WtO) {
  __shared__ u16 t[64 * 72];
  int bid = blockIdx.x;
  int tid = threadIdx.x;
  if (bid < 8192) {
    int i = bid * 256 + tid;
    float4 v = ((const float4*)x)[i];
    ushort4 h;
    h.x = f2b(v.x); h.y = f2b(v.y); h.z = f2b(v.z); h.w = f2b(v.w);
    ((ushort4*)Xb)[i] = h;
    return;
  }
  const float* in; u16* out; int N, bx, by;
  if (bid < 8960) {
    int tt = bid - 8192; bx = tt % 48; by = tt / 48; in = Wqkv; out = WtQ; N = 3072;
  } else {
    int tt = bid - 8960; bx = tt & 15; by = tt >> 4; in = Wout; out = WtO; N = 1024;
  }
  int k0 = by * 64, n0 = bx * 64;
#pragma unroll
  for (int p = 0; p < 4; ++p) {
    int idx = p * 256 + tid;
    int k = idx >> 4, ng = idx & 15;
    float4 v = *(const float4*)(in + (k0 + k) * N + n0 + ng * 4);
    t[(ng * 4 + 0) * 72 + k] = f2b(v.x);
    t[(ng * 4 + 1) * 72 + k] = f2b(v.y);
    t[(ng * 4 + 2) * 72 + k] = f2b(v.z);
    t[(ng * 4 + 3) * 72 + k] = f2b(v.w);
  }
  __syncthreads();
#pragma unroll
  for (int p = 0; p < 2; ++p) {
    int idx = p * 256 + tid;
    int n = idx >> 3, kg = (idx & 7) * 8;
    uint4 u = *(uint4*)(&t[n * 72 + kg]);
    *(uint4*)(out + (n0 + n) * 1024 + k0 + kg) = u;
  }
}

// ---------------- GEMM: C[M][N] = A[M][1024] @ Wt^T + bias ----------------
// 128x128 tile, BK=32, 4 waves. 3-buffer LDS rotation with counted
// s_waitcnt vmcnt(4) + ONE raw barrier per K-step (T4).
// MODE 0: N=3072, out -> Q/K/V bf16 [64][2048][64], q scaled by 0.125*log2(e)
// MODE 1: N=1024, out -> fp32 d_out
template <int MODE>
__global__ __launch_bounds__(256) void gemm_bf16(const u16* __restrict__ A,
                                                 const u16* __restrict__ B,
                                                 const float* __restrict__ bias,
                                                 float* __restrict__ outf,
                                                 u16* __restrict__ Qo, u16* __restrict__ Ko,
                                                 u16* __restrict__ Vo) {
  __shared__ u16 a_lds[3 * 4096];
  __shared__ u16 b_lds[3 * 4096];
  int tid = threadIdx.x;
  int l = tid & 63, w = tid >> 6;
  int wr = (w >> 1) * 64, wc = (w & 1) * 64;
  int m0 = blockIdx.y * 128, n0 = blockIdx.x * 128;
  int r15 = l & 15;
  int ka = (l >> 4) * 8;
  int r0 = tid >> 2, kg0 = (tid & 3) * 8;
  f32x4 acc[4][4] = {};

#define STAGE_G(BUF, KT)                                                                     \
  {                                                                                          \
    int kk = (KT) * 32;                                                                      \
    __builtin_amdgcn_global_load_lds(                                                        \
        (const __attribute__((address_space(1))) void*)(A + (m0 + r0) * 1024 + kk + kg0),    \
        (__attribute__((address_space(3))) void*)(&a_lds[(BUF) * 4096 + tid * 8]), 16, 0, 0);\
    __builtin_amdgcn_global_load_lds(                                                        \
        (const __attribute__((address_space(1))) void*)(A + (m0 + 64 + r0) * 1024 + kk + kg0),\
        (__attribute__((address_space(3))) void*)(&a_lds[(BUF) * 4096 + 2048 + tid * 8]), 16, 0, 0);\
    __builtin_amdgcn_global_load_lds(                                                        \
        (const __attribute__((address_space(1))) void*)(B + (n0 + r0) * 1024 + kk + kg0),    \
        (__attribute__((address_space(3))) void*)(&b_lds[(BUF) * 4096 + tid * 8]), 16, 0, 0);\
    __builtin_amdgcn_global_load_lds(                                                        \
        (const __attribute__((address_space(1))) void*)(B + (n0 + 64 + r0) * 1024 + kk + kg0),\
        (__attribute__((address_space(3))) void*)(&b_lds[(BUF) * 4096 + 2048 + tid * 8]), 16, 0, 0);\
  }

  STAGE_G(0, 0);
  int cur = 0;
#pragma unroll 1
  for (int kt = 0; kt < 32; ++kt) {
    int nxt = (cur == 2) ? 0 : cur + 1;
    if (kt < 31) {
      STAGE_G(nxt, kt + 1);
      asm volatile("s_waitcnt vmcnt(4)" ::: "memory");
    } else {
      asm volatile("s_waitcnt vmcnt(0)" ::: "memory");
    }
    __builtin_amdgcn_s_barrier();
    __builtin_amdgcn_sched_barrier(0);
    int bo = cur * 4096;
    bf16x8 af[4], bf[4];
#pragma unroll
    for (int i = 0; i < 4; ++i) {
      U4B8 ua; ua.u = *(uint4*)(&a_lds[bo + (wr + i * 16 + r15) * 32 + ka]); af[i] = ua.v;
      U4B8 ub; ub.u = *(uint4*)(&b_lds[bo + (wc + i * 16 + r15) * 32 + ka]); bf[i] = ub.v;
    }
#pragma unroll
    for (int i = 0; i < 4; ++i)
#pragma unroll
      for (int j = 0; j < 4; ++j)
        acc[i][j] = __builtin_amdgcn_mfma_f32_16x16x32_bf16(af[i], bf[j], acc[i][j], 0, 0, 0);
    cur = nxt;
  }
#undef STAGE_G

  int rbase = (l >> 4) * 4;
#pragma unroll
  for (int i = 0; i < 4; ++i)
#pragma unroll
    for (int j = 0; j < 4; ++j) {
      int n = n0 + wc + j * 16 + r15;
      float bv = bias[n];
#pragma unroll
      for (int r = 0; r < 4; ++r) {
        int m = m0 + wr + i * 16 + rbase + r;
        float val = acc[i][j][r] + bv;
        if (MODE == 0) {
          int h = n / 192, rem = n % 192;
          int part = rem >> 6, d = rem & 63;
          int b = m >> 11, s = m & 2047;
          int off = (((b * 16 + h) * 2048) + s) * 64 + d;
          // q folded scale: 0.125 * log2(e) so attention can use exp2 directly
          u16 hv = f2b(part == 0 ? val * 0.180336880111f : val);
          if (part == 0) Qo[off] = hv;
          else if (part == 1) Ko[off] = hv;
          else Vo[off] = hv;
        } else {
          outf[m * 1024 + n] = val;
        }
      }
    }
}

// ---------------- flash attention (round-16 configuration, measured best) ----------------
// 256 blocks x 1024 threads (16 waves, 512 q/block, 32 q/wave as 2 q-frags).
// 1 block/CU. Staging ROLE-SPLIT (threads <512 K via gll, >=512 V scatter).
// lsum via MFMA ones-trick. XCD remap: xcd=bid&7, bh=xcd*8+(bid>>5), qb=(bid>>3)&3.
// Swapped QK^T (16x16x32); PV via mfma_f32_16x16x16bf16_1k, reg-resident P.
// exp2 via __builtin_amdgcn_exp2f. V^T [d][kv] swz4(d)=((d>>3)^d)&15;
// K [kv][64] row&7-swizzle via pre-swizzled gll source. 32KB K/V dbuf,
// 1 barrier/tile, T14 split. NOTE: 1024-thread blocks are toolchain-pinned to
// 64 VGPR (r18/r19: both (1024,2) and (1024,1) -> 64) — this kernel fits 64
// exactly; the 128-row-tile variant (~80 regs) spills and is abandoned.
__global__ __launch_bounds__(1024, 2) void attn_fwd(const u16* __restrict__ Q,
                                                    const u16* __restrict__ K,
                                                    const u16* __restrict__ V,
                                                    u16* __restrict__ O) {
  __shared__ u16 lds[32768];  // [0,8192): K dbuf, [8192,16384): V^T dbuf, rest epilogue
  int tid = threadIdx.x;
  int l = tid & 63, w = tid >> 6;
  int g = l >> 4, r15 = l & 15, r7 = r15 & 7;
  int bid = blockIdx.x;
  int qb = (bid >> 3) & 3;
  int bh = (bid & 7) * 8 + (bid >> 5);
  const u16* Kb = K + bh * 131072;
  const u16* Vb = V + bh * 131072;
  int ka = g * 8;
  int qbase = qb * 512 + w * 32;
  U4B8 t0, t1, t2, t3;
  t0.u = *(const uint4*)(Q + bh * 131072 + (qbase + r15) * 64 + ka);
  t1.u = *(const uint4*)(Q + bh * 131072 + (qbase + r15) * 64 + 32 + ka);
  t2.u = *(const uint4*)(Q + bh * 131072 + (qbase + 16 + r15) * 64 + ka);
  t3.u = *(const uint4*)(Q + bh * 131072 + (qbase + 16 + r15) * 64 + 32 + ka);
  bf16x8 qf00 = t0.v, qf01 = t1.v, qf10 = t2.v, qf11 = t3.v;

  // K b128 read addrs: row=c*16+r15, chunk (g)^(row&7); col+32 variant = ^32
  int kaddr[4];
#pragma unroll
  for (int c = 0; c < 4; ++c) kaddr[c] = (c * 16 + r15) * 64 + ((g ^ r7) << 3);
  // V^T b64 read base (c=0): d=16dq+r15; addr(c) = vaddr0 ^ (16c)
  int vaddr0[4];
#pragma unroll
  for (int dq = 0; dq < 4; ++dq) {
    int d = r15 + 16 * dq;
    int vsw = ((d >> 3) ^ d) & 15;
    vaddr0[dq] = 8192 + d * 64 + ((g ^ vsw) << 2);
  }

  // staging role split
  int st = tid & 511;
  bool kRole = tid < 512;
  // K role: source chunk pre-swizzled (m173): row=st>>3, chunk=(st&7)^(row&7).
  int krow0 = st >> 3;
  int kcg = (((st & 7) ^ (krow0 & 7)) << 3);
  // V role: thread loads V[sr0][sdg..sdg+7], scatters transposed+swizzled.
  int sr0 = st >> 3, sdg = (st & 7) * 8;
  int vwa[8];
#pragma unroll
  for (int i = 0; i < 8; ++i) {
    int d = sdg + i;
    int sw = ((d >> 3) ^ d) & 15;
    vwa[i] = 8192 + d * 64 + ((((sr0 >> 2)) ^ sw) << 2) + (sr0 & 3);
  }
  U4B8 vreg;

#define STAGE(OFFW, TN)                                                                    \
  {                                                                                        \
    int kv0 = (TN) * 64;                                                                   \
    if (kRole) {                                                                           \
      __builtin_amdgcn_global_load_lds(                                                    \
          (const __attribute__((address_space(1))) void*)(Kb + (kv0 + krow0) * 64 + kcg),  \
          (__attribute__((address_space(3))) void*)(&lds[(OFFW) + st * 8]), 16, 0, 0);     \
    } else {                                                                               \
      vreg.u = *(const uint4*)(Vb + (kv0 + sr0) * 64 + sdg);                               \
    }                                                                                      \
  }

#define WRITEV(OFFW)                                                                       \
  {                                                                                        \
    if (!kRole) {                                                                          \
      _Pragma("unroll") for (int i = 0; i < 8; ++i) {                                      \
        lds[(OFFW) + vwa[i]] = vreg.s[i];                                                  \
      }                                                                                    \
    }                                                                                      \
  }

  s16x4 vone;
  vone[0] = (short)0x3F80; vone[1] = (short)0x3F80;
  vone[2] = (short)0x3F80; vone[3] = (short)0x3F80;
  f32x4 lacc0 = {}, lacc1 = {};
  f32x4 o0[4] = {}, o1[4] = {};

#define COMPUTE(OFFR)                                                                      \
  {                                                                                        \
    _Pragma("unroll") for (int c = 0; c < 4; ++c) {                                        \
      U4B8 k0, k1;                                                                         \
      k0.u = *(const uint4*)(&lds[(OFFR) + kaddr[c]]);                                     \
      k1.u = *(const uint4*)(&lds[(OFFR) + (kaddr[c] ^ 32)]);                              \
      f32x4 z0 = {}, z1 = {};                                                              \
      z0 = __builtin_amdgcn_mfma_f32_16x16x32_bf16(k0.v, qf00, z0, 0, 0, 0);               \
      z0 = __builtin_amdgcn_mfma_f32_16x16x32_bf16(k1.v, qf01, z0, 0, 0, 0);               \
      z1 = __builtin_amdgcn_mfma_f32_16x16x32_bf16(k0.v, qf10, z1, 0, 0, 0);               \
      z1 = __builtin_amdgcn_mfma_f32_16x16x32_bf16(k1.v, qf11, z1, 0, 0, 0);               \
      float a0 = __builtin_amdgcn_exp2f(z0[0]), a1 = __builtin_amdgcn_exp2f(z0[1]);        \
      float a2 = __builtin_amdgcn_exp2f(z0[2]), a3 = __builtin_amdgcn_exp2f(z0[3]);        \
      U2S4 pa0;                                                                            \
      pa0.h[0] = (__bf16)a0; pa0.h[1] = (__bf16)a1;                                        \
      pa0.h[2] = (__bf16)a2; pa0.h[3] = (__bf16)a3;                                        \
      float b0 = __builtin_amdgcn_exp2f(z1[0]), b1 = __builtin_amdgcn_exp2f(z1[1]);        \
      float b2 = __builtin_amdgcn_exp2f(z1[2]), b3 = __builtin_amdgcn_exp2f(z1[3]);        \
      U2S4 pa1;                                                                            \
      pa1.h[0] = (__bf16)b0; pa1.h[1] = (__bf16)b1;                                        \
      pa1.h[2] = (__bf16)b2; pa1.h[3] = (__bf16)b3;                                        \
      lacc0 = __builtin_amdgcn_mfma_f32_16x16x16bf16_1k(pa0.s, vone, lacc0, 0, 0, 0);      \
      lacc1 = __builtin_amdgcn_mfma_f32_16x16x16bf16_1k(pa1.s, vone, lacc1, 0, 0, 0);      \
      _Pragma("unroll") for (int dq = 0; dq < 4; ++dq) {                                   \
        U2S4 vb;                                                                           \
        vb.u2 = *(const uint2*)(&lds[(OFFR) + (vaddr0[dq] ^ (16 * c))]);                   \
        o0[dq] = __builtin_amdgcn_mfma_f32_16x16x16bf16_1k(pa0.s, vb.s, o0[dq], 0, 0, 0);  \
        o1[dq] = __builtin_amdgcn_mfma_f32_16x16x16bf16_1k(pa1.s, vb.s, o1[dq], 0, 0, 0);  \
      }                                                                                    \
    }                                                                                      \
  }

  STAGE(0, 0);
  WRITEV(0);
#pragma unroll 1
  for (int tt = 0; tt < 16; ++tt) {
    __syncthreads();
    STAGE(4096, 2 * tt + 1);
    COMPUTE(0);
    WRITEV(4096);
    __syncthreads();
    if (tt < 15) STAGE(0, 2 * tt + 2);
    COMPUTE(4096);
    if (tt < 15) WRITEV(0);
  }
#undef STAGE
#undef WRITEV
#undef COMPUTE

  // per-lane inverse sums: lacc[j] holds l of q-row 4g+j (C/D row = 4g+reg)
  float c0[4], c1[4];
#pragma unroll
  for (int j = 0; j < 4; ++j) {
    c0[j] = 1.f / lacc0[j];
    c1[j] = 1.f / lacc1[j];
  }
  // ---- staged O epilogue: per-wave 32x64 bf16 tile in reused LDS -> full-line stores ----
  __syncthreads();   // all waves done reading K/V buffers before reuse
  u16* stg = lds + w * 2048;   // 16 waves x 2048 u16 = 32768 (whole lds)
#pragma unroll
  for (int j = 0; j < 4; ++j) {
    int rr0 = 4 * g + j;        // (rr0>>2)&3 == g
    int rr1 = 16 + 4 * g + j;   // (rr1>>2)&3 == g
#pragma unroll
    for (int dq = 0; dq < 4; ++dq) {
      int pc = ((dq ^ g) << 4) + r15;
      stg[rr0 * 64 + pc] = f2b(o0[dq][j] * c0[j]);
      stg[rr1 * 64 + pc] = f2b(o1[dq][j] * c1[j]);
    }
  }
  int b = bh >> 4, h = bh & 15;
  int colpair = (l & 31) * 2;
  int rowsel = l >> 5;
#pragma unroll
  for (int it = 0; it < 16; ++it) {
    int rr = 2 * it + rowsel;
    int phys = rr * 64 + (((colpair >> 4) ^ ((rr >> 2) & 3)) << 4) + (colpair & 15);
    unsigned pv = *(const unsigned*)(&stg[phys]);
    int row = qbase + rr;
    *(unsigned*)(&O[(b * 2048 + row) * 1024 + h * 64 + colpair]) = pv;
  }
}

extern "C" void kernel_launch(void* const* d_in, const int* in_sizes, int n_in,
                              void* d_out, int out_size, void* d_ws, size_t ws_size,
                              hipStream_t stream) {
  const float* x = (const float*)d_in[0];
  const float* Wqkv = (const float*)d_in[1];
  const float* bqkv = (const float*)d_in[2];
  const float* Wout = (const float*)d_in[3];
  const float* bout = (const float*)d_in[4];
  float* out = (float*)d_out;

  u16* ws = (u16*)d_ws;
  u16* WtQ = ws;                    // 3072*1024
  u16* WtO = WtQ + 3072 * 1024;     // 1024*1024
  u16* Xb  = WtO + 1024 * 1024;     // 8192*1024
  u16* Qw  = Xb + 8192 * 1024;      // 64*2048*64
  u16* Kw  = Qw + 64 * 2048 * 64;
  u16* Vw  = Kw + 64 * 2048 * 64;
  u16* Aw  = Vw + 64 * 2048 * 64;   // 8192*1024

  prep<<<9216, 256, 0, stream>>>(x, Wqkv, Wout, Xb, WtQ, WtO);
  gemm_bf16<0><<<dim3(24, 64), 256, 0, stream>>>(Xb, WtQ, bqkv, nullptr, Qw, Kw, Vw);
  attn_fwd<<<256, 1024, 0, stream>>>(Qw, Kw, Vw, Aw);
  gemm_bf16<1><<<dim3(8, 64), 256, 0, stream>>>(Aw, WtO, bout, out, nullptr, nullptr, nullptr);
}